// Round 2
// baseline (1549.084 us; speedup 1.0000x reference)
//
#include <hip/hip_runtime.h>
#include <math.h>

#define NN 100000
#define EE 640000
#define DD 128
#define CC 40

// ---------------- graph preprocessing ----------------

__global__ __launch_bounds__(256) void k_deg_cnt(const int* __restrict__ dst,
                                                 const float* __restrict__ w,
                                                 float* __restrict__ deg,
                                                 int* __restrict__ cnt) {
    int e = blockIdx.x * 256 + threadIdx.x;
    if (e < EE) {
        int d = dst[e];
        atomicAdd(&deg[d], w[e]);
        atomicAdd(&cnt[d], 1);
    }
}

__global__ __launch_bounds__(256) void k_dinv(float* __restrict__ deg) {
    int i = blockIdx.x * 256 + threadIdx.x;
    // self-loop weight 1 always present -> deg+1 > 0
    if (i < NN) deg[i] = rsqrtf(deg[i] + 1.0f);
}

// chunk-wise exclusive scan: 98 blocks x 1024 elements
__global__ __launch_bounds__(256) void k_scan1(const int* __restrict__ cnt,
                                               int* __restrict__ out,
                                               int* __restrict__ partial) {
    __shared__ int lds[256];
    int t = threadIdx.x;
    int base = blockIdx.x * 1024 + t * 4;
    int v[4]; int s = 0;
    #pragma unroll
    for (int j = 0; j < 4; ++j) {
        int idx = base + j;
        v[j] = (idx < NN) ? cnt[idx] : 0;
        s += v[j];
    }
    lds[t] = s;
    __syncthreads();
    for (int off = 1; off < 256; off <<= 1) {
        int x = lds[t];
        int y = (t >= off) ? lds[t - off] : 0;
        __syncthreads();
        lds[t] = x + y;
        __syncthreads();
    }
    int excl = lds[t] - s;
    if (t == 255) partial[blockIdx.x] = lds[255];
    int run = excl;
    #pragma unroll
    for (int j = 0; j < 4; ++j) {
        int idx = base + j;
        if (idx < NN) out[idx] = run;
        run += v[j];
    }
}

__global__ __launch_bounds__(128) void k_scan2(int* __restrict__ partial) {
    __shared__ int lds[128];
    int t = threadIdx.x;
    int v = (t < 98) ? partial[t] : 0;
    lds[t] = v;
    __syncthreads();
    for (int off = 1; off < 128; off <<= 1) {
        int x = lds[t];
        int y = (t >= off) ? lds[t - off] : 0;
        __syncthreads();
        lds[t] = x + y;
        __syncthreads();
    }
    if (t < 98) partial[t] = lds[t] - v;  // exclusive
}

__global__ __launch_bounds__(256) void k_scan3(int* __restrict__ rp,
                                               const int* __restrict__ partial) {
    int i = blockIdx.x * 256 + threadIdx.x;
    if (i < NN) rp[i] += partial[i >> 10];
    if (i == 0) rp[NN] = EE;
}

__global__ __launch_bounds__(256) void k_scatter(const int* __restrict__ src,
                                                 const int* __restrict__ dst,
                                                 const float* __restrict__ w,
                                                 const float* __restrict__ dinv,
                                                 const int* __restrict__ rp,
                                                 int* __restrict__ fill,
                                                 int* __restrict__ col,
                                                 float* __restrict__ val) {
    int e = blockIdx.x * 256 + threadIdx.x;
    if (e < EE) {
        int s = src[e], d = dst[e];
        int p = rp[d] + atomicAdd(&fill[d], 1);
        col[p] = s;
        val[p] = dinv[s] * w[e] * dinv[d];
    }
}

// ---------------- dense matmuls (fp32 vector ALU) ----------------

// H[N,128] = X[N,128] @ W[128,128]; 32 rows per block, 256 threads.
__global__ __launch_bounds__(256) void k_mm128(const float* __restrict__ X,
                                               const float* __restrict__ W,
                                               float* __restrict__ H) {
    __shared__ float xs[DD * 32];  // transposed: xs[k][r], 16 KB
    __shared__ float ws[32 * DD];  // K-chunk of W: ws[kk][c], 16 KB
    int t = threadIdx.x;
    int row0 = blockIdx.x * 32;

    for (int idx = t * 4; idx < 32 * DD; idx += 1024) {
        int r = idx >> 7, k = idx & 127;
        float4 xv = *(const float4*)(X + (size_t)(row0 + r) * DD + k);
        xs[(k + 0) * 32 + r] = xv.x;
        xs[(k + 1) * 32 + r] = xv.y;
        xs[(k + 2) * 32 + r] = xv.z;
        xs[(k + 3) * 32 + r] = xv.w;
    }

    int ty = t >> 5, tx = t & 31;
    int r0 = ty * 4, c0 = tx * 4;
    float acc[4][4];
    #pragma unroll
    for (int i = 0; i < 4; ++i)
        #pragma unroll
        for (int j = 0; j < 4; ++j) acc[i][j] = 0.f;

    for (int kc = 0; kc < 4; ++kc) {
        __syncthreads();
        for (int idx = t * 4; idx < 32 * DD; idx += 1024)
            *(float4*)(ws + idx) = *(const float4*)(W + (size_t)kc * 32 * DD + idx);
        __syncthreads();
        #pragma unroll
        for (int kk = 0; kk < 32; ++kk) {
            int k = kc * 32 + kk;
            float4 xv = *(const float4*)(xs + k * 32 + r0);
            float4 wv = *(const float4*)(ws + kk * DD + c0);
            acc[0][0] += xv.x * wv.x; acc[0][1] += xv.x * wv.y; acc[0][2] += xv.x * wv.z; acc[0][3] += xv.x * wv.w;
            acc[1][0] += xv.y * wv.x; acc[1][1] += xv.y * wv.y; acc[1][2] += xv.y * wv.z; acc[1][3] += xv.y * wv.w;
            acc[2][0] += xv.z * wv.x; acc[2][1] += xv.z * wv.y; acc[2][2] += xv.z * wv.z; acc[2][3] += xv.z * wv.w;
            acc[3][0] += xv.w * wv.x; acc[3][1] += xv.w * wv.y; acc[3][2] += xv.w * wv.z; acc[3][3] += xv.w * wv.w;
        }
    }
    #pragma unroll
    for (int i = 0; i < 4; ++i) {
        float4 o; o.x = acc[i][0]; o.y = acc[i][1]; o.z = acc[i][2]; o.w = acc[i][3];
        *(float4*)(H + (size_t)(row0 + r0 + i) * DD + c0) = o;
    }
}

// H[N,40] = X[N,128] @ Wf[128,40]; one thread per output element.
__global__ __launch_bounds__(256) void k_mm40(const float* __restrict__ X,
                                              const float* __restrict__ W,
                                              float* __restrict__ H) {
    __shared__ float ws[DD * CC];  // 20 KB
    int t = threadIdx.x;
    for (int i = t; i < DD * CC; i += 256) ws[i] = W[i];
    __syncthreads();
    int idx = blockIdx.x * 256 + t;  // grid covers exactly NN*CC
    int row = idx / CC, c = idx % CC;
    const float* xr = X + (size_t)row * DD;
    float acc = 0.f;
    #pragma unroll 8
    for (int k = 0; k < DD; ++k) acc += xr[k] * ws[k * CC + c];
    H[idx] = acc;
}

// ---------------- aggregation (CSR, wave per node) ----------------

__global__ __launch_bounds__(256) void k_agg128(const float* __restrict__ h,
                                                const float* __restrict__ dinv,
                                                const int* __restrict__ rp,
                                                const int* __restrict__ col,
                                                const float* __restrict__ val,
                                                const float* __restrict__ bias,
                                                float* __restrict__ out,
                                                int relu) {
    int node = blockIdx.x * 4 + (threadIdx.x >> 6);
    int lane = threadIdx.x & 63;
    if (node >= NN) return;
    const float2* h2 = (const float2*)h;
    float dv = dinv[node];
    float2 hv = h2[(size_t)node * 64 + lane];
    float ax = hv.x * dv * dv;
    float ay = hv.y * dv * dv;
    int beg = rp[node], end = rp[node + 1];
    for (int e = beg; e < end; ++e) {
        int s = col[e];
        float v = val[e];
        float2 q = h2[(size_t)s * 64 + lane];
        ax += v * q.x;
        ay += v * q.y;
    }
    float2 bz = ((const float2*)bias)[lane];
    ax += bz.x; ay += bz.y;
    if (relu) { ax = fmaxf(ax, 0.f); ay = fmaxf(ay, 0.f); }
    float2 r; r.x = ax; r.y = ay;
    ((float2*)out)[(size_t)node * 64 + lane] = r;
}

__global__ __launch_bounds__(256) void k_agg40(const float* __restrict__ h,
                                               const float* __restrict__ dinv,
                                               const int* __restrict__ rp,
                                               const int* __restrict__ col,
                                               const float* __restrict__ val,
                                               const float* __restrict__ bias,
                                               float* __restrict__ out) {
    int node = blockIdx.x * 4 + (threadIdx.x >> 6);
    int lane = threadIdx.x & 63;
    if (node >= NN) return;
    if (lane >= CC) return;
    float dv = dinv[node];
    float acc = h[(size_t)node * CC + lane] * dv * dv;
    int beg = rp[node], end = rp[node + 1];
    for (int e = beg; e < end; ++e)
        acc += val[e] * h[(size_t)col[e] * CC + lane];
    out[(size_t)node * CC + lane] = acc + bias[lane];
}

// row L2-normalize C, then A = (normalize(C) + A) / 2
__global__ __launch_bounds__(256) void k_normres(float* __restrict__ A,
                                                 const float* __restrict__ Cb) {
    int node = blockIdx.x * 4 + (threadIdx.x >> 6);
    int lane = threadIdx.x & 63;
    if (node >= NN) return;
    const float2* c2 = (const float2*)Cb;
    float2* a2 = (float2*)A;
    float2 c = c2[(size_t)node * 64 + lane];
    float ss = c.x * c.x + c.y * c.y;
    #pragma unroll
    for (int off = 32; off > 0; off >>= 1) ss += __shfl_xor(ss, off);
    float nrm = sqrtf(ss);
    float sc = 1.0f / fmaxf(nrm, 1e-12f);
    float2 a = a2[(size_t)node * 64 + lane];
    a.x = (c.x * sc + a.x) * 0.5f;
    a.y = (c.y * sc + a.y) * 0.5f;
    a2[(size_t)node * 64 + lane] = a;
}

__global__ __launch_bounds__(256) void k_logsm(const float* __restrict__ Cb,
                                               float* __restrict__ out) {
    int node = blockIdx.x * 4 + (threadIdx.x >> 6);
    int lane = threadIdx.x & 63;
    if (node >= NN) return;
    float v = (lane < CC) ? Cb[(size_t)node * CC + lane] : -3.0e38f;
    float m = v;
    #pragma unroll
    for (int off = 32; off > 0; off >>= 1) m = fmaxf(m, __shfl_xor(m, off));
    float e = (lane < CC) ? expf(v - m) : 0.f;
    float s = e;
    #pragma unroll
    for (int off = 32; off > 0; off >>= 1) s += __shfl_xor(s, off);
    if (lane < CC) out[(size_t)node * CC + lane] = v - m - logf(s);
}

// ---------------- launch ----------------

extern "C" void kernel_launch(void* const* d_in, const int* in_sizes, int n_in,
                              void* d_out, int out_size, void* d_ws, size_t ws_size,
                              hipStream_t stream) {
    const float* x  = (const float*)d_in[0];
    const int*   ei = (const int*)d_in[1];
    const float* ew = (const float*)d_in[2];
    const float* Wb = (const float*)d_in[3];
    const float* bb = (const float*)d_in[4];
    const float* Wf = (const float*)d_in[5];
    const float* bf = (const float*)d_in[6];
    const int* src = ei;
    const int* dst = ei + EE;
    float* out = (float*)d_out;

    char* p = (char*)d_ws;
    float* A    = (float*)p; p += (size_t)NN * DD * 4;
    float* B    = (float*)p; p += (size_t)NN * DD * 4;
    float* Cb   = (float*)p; p += (size_t)NN * DD * 4;
    float* dinv = (float*)p; p += (size_t)NN * 4;
    int*   cnt  = (int*)p;   p += (size_t)NN * 4;
    int*   rp   = (int*)p;   p += (size_t)(NN + 1) * 4;
    int*   fill = (int*)p;   p += (size_t)NN * 4;
    int*   col  = (int*)p;   p += (size_t)EE * 4;
    float* val  = (float*)p; p += (size_t)EE * 4;
    int*   partial = (int*)p; p += 128 * 4;

    hipMemsetAsync(dinv, 0, (size_t)NN * 4, stream);
    hipMemsetAsync(cnt,  0, (size_t)NN * 4, stream);
    hipMemsetAsync(fill, 0, (size_t)NN * 4, stream);

    k_deg_cnt<<<(EE + 255) / 256, 256, 0, stream>>>(dst, ew, dinv, cnt);
    k_dinv<<<(NN + 255) / 256, 256, 0, stream>>>(dinv);
    k_scan1<<<98, 256, 0, stream>>>(cnt, rp, partial);
    k_scan2<<<1, 128, 0, stream>>>(partial);
    k_scan3<<<(NN + 255) / 256, 256, 0, stream>>>(rp, partial);
    k_scatter<<<(EE + 255) / 256, 256, 0, stream>>>(src, dst, ew, dinv, rp, fill, col, val);

    hipMemcpyAsync(A, x, (size_t)NN * DD * 4, hipMemcpyDeviceToDevice, stream);

    for (int blk = 0; blk < 4; ++blk) {
        k_mm128<<<NN / 32, 256, 0, stream>>>(A, Wb + (size_t)(2 * blk) * DD * DD, B);
        k_agg128<<<NN / 4, 256, 0, stream>>>(B, dinv, rp, col, val, bb + (size_t)(2 * blk) * DD, Cb, 1);
        k_mm128<<<NN / 32, 256, 0, stream>>>(Cb, Wb + (size_t)(2 * blk + 1) * DD * DD, B);
        k_agg128<<<NN / 4, 256, 0, stream>>>(B, dinv, rp, col, val, bb + (size_t)(2 * blk + 1) * DD, Cb, 1);
        k_normres<<<NN / 4, 256, 0, stream>>>(A, Cb);
    }
    k_mm40<<<(NN * CC) / 256, 256, 0, stream>>>(A, Wf, B);
    k_agg40<<<NN / 4, 256, 0, stream>>>(B, dinv, rp, col, val, bf, Cb);
    k_logsm<<<NN / 4, 256, 0, stream>>>(Cb, out);
}

// Round 3
// 935.275 us; speedup vs baseline: 1.6563x; 1.6563x over previous
//
#include <hip/hip_runtime.h>
#include <math.h>

#define NN 100000
#define EE 640000
#define DD 128
#define CC 40

typedef __bf16 bf16x8 __attribute__((ext_vector_type(8)));
typedef float f32x4 __attribute__((ext_vector_type(4)));
typedef unsigned short us8 __attribute__((ext_vector_type(8)));

__device__ inline unsigned short f2b(float f) {
    union { float f; unsigned u; } v; v.f = f;
    unsigned u = v.u;
    return (unsigned short)((u + 0x7FFFu + ((u >> 16) & 1u)) >> 16);
}
__device__ inline float b2f(unsigned short b) {
    union { unsigned u; float f; } v; v.u = ((unsigned)b) << 16;
    return v.f;
}

// ---------------- graph preprocessing ----------------

__global__ __launch_bounds__(256) void k_deg_cnt(const int* __restrict__ dst,
                                                 const float* __restrict__ w,
                                                 float* __restrict__ deg,
                                                 int* __restrict__ cnt) {
    int e = blockIdx.x * 256 + threadIdx.x;
    if (e < EE) {
        int d = dst[e];
        atomicAdd(&deg[d], w[e]);
        atomicAdd(&cnt[d], 1);
    }
}

__global__ __launch_bounds__(256) void k_dinv(float* __restrict__ deg) {
    int i = blockIdx.x * 256 + threadIdx.x;
    if (i < NN) deg[i] = rsqrtf(deg[i] + 1.0f);  // self-loop weight 1
}

__global__ __launch_bounds__(256) void k_scan1(const int* __restrict__ cnt,
                                               int* __restrict__ out,
                                               int* __restrict__ partial) {
    __shared__ int lds[256];
    int t = threadIdx.x;
    int base = blockIdx.x * 1024 + t * 4;
    int v[4]; int s = 0;
    #pragma unroll
    for (int j = 0; j < 4; ++j) {
        int idx = base + j;
        v[j] = (idx < NN) ? cnt[idx] : 0;
        s += v[j];
    }
    lds[t] = s;
    __syncthreads();
    for (int off = 1; off < 256; off <<= 1) {
        int x = lds[t];
        int y = (t >= off) ? lds[t - off] : 0;
        __syncthreads();
        lds[t] = x + y;
        __syncthreads();
    }
    int excl = lds[t] - s;
    if (t == 255) partial[blockIdx.x] = lds[255];
    int run = excl;
    #pragma unroll
    for (int j = 0; j < 4; ++j) {
        int idx = base + j;
        if (idx < NN) out[idx] = run;
        run += v[j];
    }
}

__global__ __launch_bounds__(128) void k_scan2(int* __restrict__ partial) {
    __shared__ int lds[128];
    int t = threadIdx.x;
    int v = (t < 98) ? partial[t] : 0;
    lds[t] = v;
    __syncthreads();
    for (int off = 1; off < 128; off <<= 1) {
        int x = lds[t];
        int y = (t >= off) ? lds[t - off] : 0;
        __syncthreads();
        lds[t] = x + y;
        __syncthreads();
    }
    if (t < 98) partial[t] = lds[t] - v;
}

__global__ __launch_bounds__(256) void k_scan3(int* __restrict__ rp,
                                               const int* __restrict__ partial) {
    int i = blockIdx.x * 256 + threadIdx.x;
    if (i < NN) rp[i] += partial[i >> 10];
    if (i == 0) rp[NN] = EE;
}

__global__ __launch_bounds__(256) void k_scatter(const int* __restrict__ src,
                                                 const int* __restrict__ dst,
                                                 const float* __restrict__ w,
                                                 const float* __restrict__ dinv,
                                                 const int* __restrict__ rp,
                                                 int* __restrict__ fill,
                                                 int* __restrict__ col,
                                                 float* __restrict__ val) {
    int e = blockIdx.x * 256 + threadIdx.x;
    if (e < EE) {
        int s = src[e], d = dst[e];
        int p = rp[d] + atomicAdd(&fill[d], 1);
        col[p] = s;
        val[p] = dinv[s] * w[e] * dinv[d];
    }
}

// ---------------- weight / input prep ----------------

// WT[m][n][k] = bf16(W[m][k][n]) : transposed so MFMA B-frag loads are contiguous in k
__global__ __launch_bounds__(256) void k_prep_w(const float* __restrict__ Wb,
                                                unsigned short* __restrict__ WT) {
    int idx = blockIdx.x * 256 + threadIdx.x;
    if (idx >= 8 * DD * DD) return;
    int m = idx >> 14;
    int n = (idx >> 7) & 127;
    int k = idx & 127;
    WT[idx] = f2b(Wb[(size_t)m * DD * DD + (size_t)k * DD + n]);
}

// A = x (fp32 residual path), Abf = bf16(x)
__global__ __launch_bounds__(256) void k_x2bf(const float* __restrict__ x,
                                              float* __restrict__ A,
                                              unsigned short* __restrict__ Abf) {
    int idx = blockIdx.x * 256 + threadIdx.x;  // over NN*DD/4 float4s
    if (idx >= NN * DD / 4) return;
    float4 v = ((const float4*)x)[idx];
    ((float4*)A)[idx] = v;
    ushort4 r;
    r.x = f2b(v.x); r.y = f2b(v.y); r.z = f2b(v.z); r.w = f2b(v.w);
    ((ushort4*)Abf)[idx] = r;
}

// ---------------- bf16 MFMA matmul: H[N,128] = X[N,128] @ W ----------------
// block = 256 threads = 4 waves; wave computes 16 rows x 128 cols.
__global__ __launch_bounds__(256) void k_mm_mfma(const unsigned short* __restrict__ X,
                                                 const unsigned short* __restrict__ WT,
                                                 unsigned short* __restrict__ H) {
    int wid = threadIdx.x >> 6;
    int lane = threadIdx.x & 63;
    int r0 = blockIdx.x * 64 + wid * 16;
    int sl = lane & 15, g = lane >> 4;
    int arow = r0 + sl;
    if (arow >= NN) arow = NN - 1;  // clamp (stores guarded)

    f32x4 acc[8];
    #pragma unroll
    for (int n = 0; n < 8; ++n) acc[n] = (f32x4){0.f, 0.f, 0.f, 0.f};

    const bf16x8* xrow = (const bf16x8*)(X + (size_t)arow * DD);
    #pragma unroll
    for (int kc = 0; kc < 4; ++kc) {
        bf16x8 a = xrow[kc * 4 + g];
        #pragma unroll
        for (int n = 0; n < 8; ++n) {
            const bf16x8* wrow = (const bf16x8*)(WT + (size_t)(n * 16 + sl) * DD);
            bf16x8 b = wrow[kc * 4 + g];
            acc[n] = __builtin_amdgcn_mfma_f32_16x16x32_bf16(a, b, acc[n], 0, 0, 0);
        }
    }
    // C/D: col = lane&15, row = (lane>>4)*4 + v  [m89-verified mapping]
    #pragma unroll
    for (int n = 0; n < 8; ++n) {
        #pragma unroll
        for (int v = 0; v < 4; ++v) {
            int row = r0 + g * 4 + v;
            if (row < NN) H[(size_t)row * DD + n * 16 + sl] = f2b(acc[n][v]);
        }
    }
}

// ---------------- aggregation: 16 lanes/node, bf16 rows ----------------
// out = relu(sum_e norm_e * h[src_e] + dinv^2 * h[node] + bias)
__global__ __launch_bounds__(256) void k_agg128(const unsigned short* __restrict__ h,
                                                const float* __restrict__ dinv,
                                                const int* __restrict__ rp,
                                                const int* __restrict__ col,
                                                const float* __restrict__ val,
                                                const float* __restrict__ bias,
                                                unsigned short* __restrict__ outb) {
    int node = blockIdx.x * 16 + (threadIdx.x >> 4);
    int sl = threadIdx.x & 15;
    if (node >= NN) return;

    float dv = dinv[node];
    float dv2 = dv * dv;
    us8 m = ((const us8*)(h + (size_t)node * DD))[sl];
    float a[8];
    #pragma unroll
    for (int j = 0; j < 8; ++j) a[j] = dv2 * b2f(m[j]);

    int e = rp[node], end = rp[node + 1];
    for (; e + 2 <= end; e += 2) {
        int s0 = col[e], s1 = col[e + 1];
        float v0 = val[e], v1 = val[e + 1];
        us8 q0 = ((const us8*)(h + (size_t)s0 * DD))[sl];
        us8 q1 = ((const us8*)(h + (size_t)s1 * DD))[sl];
        #pragma unroll
        for (int j = 0; j < 8; ++j) a[j] += v0 * b2f(q0[j]) + v1 * b2f(q1[j]);
    }
    if (e < end) {
        int s0 = col[e];
        float v0 = val[e];
        us8 q0 = ((const us8*)(h + (size_t)s0 * DD))[sl];
        #pragma unroll
        for (int j = 0; j < 8; ++j) a[j] += v0 * b2f(q0[j]);
    }

    float4 bz0 = ((const float4*)bias)[sl * 2];
    float4 bz1 = ((const float4*)bias)[sl * 2 + 1];
    float bb[8] = {bz0.x, bz0.y, bz0.z, bz0.w, bz1.x, bz1.y, bz1.z, bz1.w};
    us8 r;
    #pragma unroll
    for (int j = 0; j < 8; ++j) r[j] = f2b(fmaxf(a[j] + bb[j], 0.f));
    ((us8*)(outb + (size_t)node * DD))[sl] = r;
}

// row L2-normalize Cb, then A = (normalize(Cb) + A)/2 (fp32), Abf = bf16(A)
__global__ __launch_bounds__(256) void k_normres(float* __restrict__ A,
                                                 unsigned short* __restrict__ Abf,
                                                 const unsigned short* __restrict__ Cb) {
    int node = blockIdx.x * 16 + (threadIdx.x >> 4);
    int sl = threadIdx.x & 15;
    if (node >= NN) return;
    us8 c = ((const us8*)(Cb + (size_t)node * DD))[sl];
    float cf[8];
    float ss = 0.f;
    #pragma unroll
    for (int j = 0; j < 8; ++j) { cf[j] = b2f(c[j]); ss += cf[j] * cf[j]; }
    ss += __shfl_xor(ss, 1);
    ss += __shfl_xor(ss, 2);
    ss += __shfl_xor(ss, 4);
    ss += __shfl_xor(ss, 8);
    float sc = 1.0f / fmaxf(sqrtf(ss), 1e-12f);
    float4 a0 = ((const float4*)(A + (size_t)node * DD))[sl * 2];
    float4 a1 = ((const float4*)(A + (size_t)node * DD))[sl * 2 + 1];
    float av[8] = {a0.x, a0.y, a0.z, a0.w, a1.x, a1.y, a1.z, a1.w};
    us8 rb;
    #pragma unroll
    for (int j = 0; j < 8; ++j) {
        av[j] = (cf[j] * sc + av[j]) * 0.5f;
        rb[j] = f2b(av[j]);
    }
    float4 o0 = {av[0], av[1], av[2], av[3]};
    float4 o1 = {av[4], av[5], av[6], av[7]};
    ((float4*)(A + (size_t)node * DD))[sl * 2] = o0;
    ((float4*)(A + (size_t)node * DD))[sl * 2 + 1] = o1;
    ((us8*)(Abf + (size_t)node * DD))[sl] = rb;
}

// ---------------- final layer (fp32) ----------------

__global__ __launch_bounds__(256) void k_mm40(const float* __restrict__ X,
                                              const float* __restrict__ W,
                                              float* __restrict__ H) {
    __shared__ float ws[DD * CC];
    int t = threadIdx.x;
    for (int i = t; i < DD * CC; i += 256) ws[i] = W[i];
    __syncthreads();
    int idx = blockIdx.x * 256 + t;
    int row = idx / CC, c = idx % CC;
    const float* xr = X + (size_t)row * DD;
    float acc = 0.f;
    #pragma unroll 8
    for (int k = 0; k < DD; ++k) acc += xr[k] * ws[k * CC + c];
    H[idx] = acc;
}

__global__ __launch_bounds__(256) void k_agg40(const float* __restrict__ h,
                                               const float* __restrict__ dinv,
                                               const int* __restrict__ rp,
                                               const int* __restrict__ col,
                                               const float* __restrict__ val,
                                               const float* __restrict__ bias,
                                               float* __restrict__ out) {
    int node = blockIdx.x * 4 + (threadIdx.x >> 6);
    int lane = threadIdx.x & 63;
    if (node >= NN) return;
    if (lane >= CC) return;
    float dv = dinv[node];
    float acc = h[(size_t)node * CC + lane] * dv * dv;
    int beg = rp[node], end = rp[node + 1];
    for (int e = beg; e < end; ++e)
        acc += val[e] * h[(size_t)col[e] * CC + lane];
    out[(size_t)node * CC + lane] = acc + bias[lane];
}

__global__ __launch_bounds__(256) void k_logsm(const float* __restrict__ Cb,
                                               float* __restrict__ out) {
    int node = blockIdx.x * 4 + (threadIdx.x >> 6);
    int lane = threadIdx.x & 63;
    if (node >= NN) return;
    float v = (lane < CC) ? Cb[(size_t)node * CC + lane] : -3.0e38f;
    float m = v;
    #pragma unroll
    for (int off = 32; off > 0; off >>= 1) m = fmaxf(m, __shfl_xor(m, off));
    float e = (lane < CC) ? expf(v - m) : 0.f;
    float s = e;
    #pragma unroll
    for (int off = 32; off > 0; off >>= 1) s += __shfl_xor(s, off);
    if (lane < CC) out[(size_t)node * CC + lane] = v - m - logf(s);
}

// ---------------- launch ----------------

extern "C" void kernel_launch(void* const* d_in, const int* in_sizes, int n_in,
                              void* d_out, int out_size, void* d_ws, size_t ws_size,
                              hipStream_t stream) {
    const float* x  = (const float*)d_in[0];
    const int*   ei = (const int*)d_in[1];
    const float* ew = (const float*)d_in[2];
    const float* Wb = (const float*)d_in[3];
    const float* bb = (const float*)d_in[4];
    const float* Wf = (const float*)d_in[5];
    const float* bf = (const float*)d_in[6];
    const int* src = ei;
    const int* dst = ei + EE;
    float* out = (float*)d_out;

    char* p = (char*)d_ws;
    float*          A    = (float*)p;          p += (size_t)NN * DD * 4;
    unsigned short* Abf  = (unsigned short*)p; p += (size_t)NN * DD * 2;
    unsigned short* Bbf  = (unsigned short*)p; p += (size_t)NN * DD * 2;
    unsigned short* Cbf  = (unsigned short*)p; p += (size_t)NN * DD * 2;
    float*          H40  = (float*)p;          p += (size_t)NN * CC * 4;
    float*          C40  = (float*)p;          p += (size_t)NN * CC * 4;
    unsigned short* WT   = (unsigned short*)p; p += (size_t)8 * DD * DD * 2;
    float* dinv = (float*)p; p += (size_t)NN * 4;
    int*   cnt  = (int*)p;   p += (size_t)NN * 4;
    int*   rp   = (int*)p;   p += (size_t)(NN + 1) * 4;
    int*   fill = (int*)p;   p += (size_t)NN * 4;
    int*   col  = (int*)p;   p += (size_t)EE * 4;
    float* val  = (float*)p; p += (size_t)EE * 4;
    int*   partial = (int*)p; p += 128 * 4;

    hipMemsetAsync(dinv, 0, (size_t)NN * 4, stream);
    hipMemsetAsync(cnt,  0, (size_t)NN * 4, stream);
    hipMemsetAsync(fill, 0, (size_t)NN * 4, stream);

    k_deg_cnt<<<(EE + 255) / 256, 256, 0, stream>>>(dst, ew, dinv, cnt);
    k_dinv<<<(NN + 255) / 256, 256, 0, stream>>>(dinv);
    k_scan1<<<98, 256, 0, stream>>>(cnt, rp, partial);
    k_scan2<<<1, 128, 0, stream>>>(partial);
    k_scan3<<<(NN + 255) / 256, 256, 0, stream>>>(rp, partial);
    k_scatter<<<(EE + 255) / 256, 256, 0, stream>>>(src, dst, ew, dinv, rp, fill, col, val);

    k_prep_w<<<(8 * DD * DD + 255) / 256, 256, 0, stream>>>(Wb, WT);
    k_x2bf<<<(NN * DD / 4 + 255) / 256, 256, 0, stream>>>(x, A, Abf);

    for (int blk = 0; blk < 4; ++blk) {
        k_mm_mfma<<<(NN + 63) / 64, 256, 0, stream>>>(Abf, WT + (size_t)(2 * blk) * DD * DD, Bbf);
        k_agg128<<<(NN + 15) / 16, 256, 0, stream>>>(Bbf, dinv, rp, col, val, bb + (size_t)(2 * blk) * DD, Cbf);
        k_mm_mfma<<<(NN + 63) / 64, 256, 0, stream>>>(Cbf, WT + (size_t)(2 * blk + 1) * DD * DD, Bbf);
        k_agg128<<<(NN + 15) / 16, 256, 0, stream>>>(Bbf, dinv, rp, col, val, bb + (size_t)(2 * blk + 1) * DD, Cbf);
        k_normres<<<(NN + 15) / 16, 256, 0, stream>>>(A, Abf, Cbf);
    }
    k_mm40<<<(NN * CC) / 256, 256, 0, stream>>>(A, Wf, H40);
    k_agg40<<<(NN + 3) / 4, 256, 0, stream>>>(H40, dinv, rp, col, val, bf, C40);
    k_logsm<<<(NN + 3) / 4, 256, 0, stream>>>(C40, out);
}

// Round 4
// 793.446 us; speedup vs baseline: 1.9523x; 1.1788x over previous
//
#include <hip/hip_runtime.h>
#include <math.h>

#define NN 100000
#define EE 640000
#define DD 128
#define CC 40

typedef __bf16 bf16x8 __attribute__((ext_vector_type(8)));
typedef float f32x4 __attribute__((ext_vector_type(4)));
typedef unsigned short us8 __attribute__((ext_vector_type(8)));

__device__ inline unsigned short f2b(float f) {
    union { float f; unsigned u; } v; v.f = f;
    unsigned u = v.u;
    return (unsigned short)((u + 0x7FFFu + ((u >> 16) & 1u)) >> 16);
}
__device__ inline float b2f(unsigned short b) {
    union { unsigned u; float f; } v; v.u = ((unsigned)b) << 16;
    return v.f;
}

// ---------------- graph preprocessing ----------------

__global__ __launch_bounds__(256) void k_deg_cnt(const int* __restrict__ dst,
                                                 const float* __restrict__ w,
                                                 float* __restrict__ deg,
                                                 int* __restrict__ cnt) {
    int e = blockIdx.x * 256 + threadIdx.x;
    if (e < EE) {
        int d = dst[e];
        atomicAdd(&deg[d], w[e]);
        atomicAdd(&cnt[d], 1);
    }
}

__global__ __launch_bounds__(256) void k_dinv(float* __restrict__ deg) {
    int i = blockIdx.x * 256 + threadIdx.x;
    if (i < NN) deg[i] = rsqrtf(deg[i] + 1.0f);  // self-loop weight 1
}

__global__ __launch_bounds__(256) void k_scan1(const int* __restrict__ cnt,
                                               int* __restrict__ out,
                                               int* __restrict__ partial) {
    __shared__ int lds[256];
    int t = threadIdx.x;
    int base = blockIdx.x * 1024 + t * 4;
    int v[4]; int s = 0;
    #pragma unroll
    for (int j = 0; j < 4; ++j) {
        int idx = base + j;
        v[j] = (idx < NN) ? cnt[idx] : 0;
        s += v[j];
    }
    lds[t] = s;
    __syncthreads();
    for (int off = 1; off < 256; off <<= 1) {
        int x = lds[t];
        int y = (t >= off) ? lds[t - off] : 0;
        __syncthreads();
        lds[t] = x + y;
        __syncthreads();
    }
    int excl = lds[t] - s;
    if (t == 255) partial[blockIdx.x] = lds[255];
    int run = excl;
    #pragma unroll
    for (int j = 0; j < 4; ++j) {
        int idx = base + j;
        if (idx < NN) out[idx] = run;
        run += v[j];
    }
}

__global__ __launch_bounds__(128) void k_scan2(int* __restrict__ partial) {
    __shared__ int lds[128];
    int t = threadIdx.x;
    int v = (t < 98) ? partial[t] : 0;
    lds[t] = v;
    __syncthreads();
    for (int off = 1; off < 128; off <<= 1) {
        int x = lds[t];
        int y = (t >= off) ? lds[t - off] : 0;
        __syncthreads();
        lds[t] = x + y;
        __syncthreads();
    }
    if (t < 98) partial[t] = lds[t] - v;
}

__global__ __launch_bounds__(256) void k_scan3(int* __restrict__ rp,
                                               const int* __restrict__ partial) {
    int i = blockIdx.x * 256 + threadIdx.x;
    if (i < NN) rp[i] += partial[i >> 10];
    if (i == 0) rp[NN] = EE;
}

__global__ __launch_bounds__(256) void k_scatter(const int* __restrict__ src,
                                                 const int* __restrict__ dst,
                                                 const float* __restrict__ w,
                                                 const float* __restrict__ dinv,
                                                 const int* __restrict__ rp,
                                                 int* __restrict__ fill,
                                                 int* __restrict__ col,
                                                 float* __restrict__ val) {
    int e = blockIdx.x * 256 + threadIdx.x;
    if (e < EE) {
        int s = src[e], d = dst[e];
        int p = rp[d] + atomicAdd(&fill[d], 1);
        col[p] = s;
        val[p] = dinv[s] * w[e] * dinv[d];
    }
}

// ---------------- weight / input prep ----------------

// WT[m][n][k] = bf16(W[m][k][n])
__global__ __launch_bounds__(256) void k_prep_w(const float* __restrict__ Wb,
                                                unsigned short* __restrict__ WT) {
    int idx = blockIdx.x * 256 + threadIdx.x;
    if (idx >= 8 * DD * DD) return;
    int m = idx >> 14;
    int n = (idx >> 7) & 127;
    int k = idx & 127;
    WT[idx] = f2b(Wb[(size_t)m * DD * DD + (size_t)k * DD + n]);
}

// WfT[n][k] = bf16(Wf[k][n]) for n<40, 0 for 40<=n<48
__global__ __launch_bounds__(256) void k_prep_wf(const float* __restrict__ Wf,
                                                 unsigned short* __restrict__ WfT) {
    int idx = blockIdx.x * 256 + threadIdx.x;
    if (idx >= 48 * DD) return;
    int n = idx >> 7;
    int k = idx & 127;
    WfT[idx] = (n < CC) ? f2b(Wf[(size_t)k * CC + n]) : 0;
}

// A = x (fp32 residual path), Abf = bf16(x)
__global__ __launch_bounds__(256) void k_x2bf(const float* __restrict__ x,
                                              float* __restrict__ A,
                                              unsigned short* __restrict__ Abf) {
    int idx = blockIdx.x * 256 + threadIdx.x;
    if (idx >= NN * DD / 4) return;
    float4 v = ((const float4*)x)[idx];
    ((float4*)A)[idx] = v;
    ushort4 r;
    r.x = f2b(v.x); r.y = f2b(v.y); r.z = f2b(v.z); r.w = f2b(v.w);
    ((ushort4*)Abf)[idx] = r;
}

// ---------------- bf16 MFMA matmul: H[N,128] = X[N,128] @ W ----------------
__global__ __launch_bounds__(256) void k_mm_mfma(const unsigned short* __restrict__ X,
                                                 const unsigned short* __restrict__ WT,
                                                 unsigned short* __restrict__ H) {
    int wid = threadIdx.x >> 6;
    int lane = threadIdx.x & 63;
    int r0 = blockIdx.x * 64 + wid * 16;
    int sl = lane & 15, g = lane >> 4;
    int arow = r0 + sl;
    if (arow >= NN) arow = NN - 1;

    f32x4 acc[8];
    #pragma unroll
    for (int n = 0; n < 8; ++n) acc[n] = (f32x4){0.f, 0.f, 0.f, 0.f};

    const bf16x8* xrow = (const bf16x8*)(X + (size_t)arow * DD);
    #pragma unroll
    for (int kc = 0; kc < 4; ++kc) {
        bf16x8 a = xrow[kc * 4 + g];
        #pragma unroll
        for (int n = 0; n < 8; ++n) {
            const bf16x8* wrow = (const bf16x8*)(WT + (size_t)(n * 16 + sl) * DD);
            bf16x8 b = wrow[kc * 4 + g];
            acc[n] = __builtin_amdgcn_mfma_f32_16x16x32_bf16(a, b, acc[n], 0, 0, 0);
        }
    }
    #pragma unroll
    for (int n = 0; n < 8; ++n) {
        #pragma unroll
        for (int v = 0; v < 4; ++v) {
            int row = r0 + g * 4 + v;
            if (row < NN) H[(size_t)row * DD + n * 16 + sl] = f2b(acc[n][v]);
        }
    }
}

// final projection: C40[N,40] = G[N,128] @ WfT^T + bf  (N padded to 48)
__global__ __launch_bounds__(256) void k_mm_final(const unsigned short* __restrict__ X,
                                                  const unsigned short* __restrict__ WfT,
                                                  const float* __restrict__ bf_,
                                                  float* __restrict__ C40) {
    int wid = threadIdx.x >> 6;
    int lane = threadIdx.x & 63;
    int r0 = blockIdx.x * 64 + wid * 16;
    int sl = lane & 15, g = lane >> 4;
    int arow = r0 + sl;
    if (arow >= NN) arow = NN - 1;

    f32x4 acc[3];
    #pragma unroll
    for (int n = 0; n < 3; ++n) acc[n] = (f32x4){0.f, 0.f, 0.f, 0.f};

    const bf16x8* xrow = (const bf16x8*)(X + (size_t)arow * DD);
    #pragma unroll
    for (int kc = 0; kc < 4; ++kc) {
        bf16x8 a = xrow[kc * 4 + g];
        #pragma unroll
        for (int n = 0; n < 3; ++n) {
            const bf16x8* wrow = (const bf16x8*)(WfT + (size_t)(n * 16 + sl) * DD);
            bf16x8 b = wrow[kc * 4 + g];
            acc[n] = __builtin_amdgcn_mfma_f32_16x16x32_bf16(a, b, acc[n], 0, 0, 0);
        }
    }
    #pragma unroll
    for (int n = 0; n < 3; ++n) {
        int c = n * 16 + sl;
        #pragma unroll
        for (int v = 0; v < 4; ++v) {
            int row = r0 + g * 4 + v;
            if (row < NN && c < CC) C40[(size_t)row * CC + c] = acc[n][v] + bf_[c];
        }
    }
}

// ---------------- aggregation kernels (16 lanes/node, bf16 rows) ----------------

// generic agg core: a[8] = dinv^2*h[node] + sum_e val*h[col]
#define AGG_CORE(h_, node_, sl_, a_)                                        \
    {                                                                       \
        float dv = dinv[node_];                                             \
        float dv2 = dv * dv;                                                \
        us8 m_ = ((const us8*)(h_ + (size_t)node_ * DD))[sl_];              \
        _Pragma("unroll")                                                   \
        for (int j = 0; j < 8; ++j) a_[j] = dv2 * b2f(m_[j]);               \
        int e = rp[node_], end = rp[node_ + 1];                             \
        for (; e + 2 <= end; e += 2) {                                      \
            int s0 = col[e], s1 = col[e + 1];                               \
            float v0 = val[e], v1 = val[e + 1];                             \
            us8 q0 = ((const us8*)(h_ + (size_t)s0 * DD))[sl_];             \
            us8 q1 = ((const us8*)(h_ + (size_t)s1 * DD))[sl_];             \
            _Pragma("unroll")                                               \
            for (int j = 0; j < 8; ++j) a_[j] += v0 * b2f(q0[j]) + v1 * b2f(q1[j]); \
        }                                                                   \
        if (e < end) {                                                      \
            int s0 = col[e];                                                \
            float v0 = val[e];                                              \
            us8 q0 = ((const us8*)(h_ + (size_t)s0 * DD))[sl_];             \
            _Pragma("unroll")                                               \
            for (int j = 0; j < 8; ++j) a_[j] += v0 * b2f(q0[j]);           \
        }                                                                   \
    }

// agg + bias + relu -> bf16
__global__ __launch_bounds__(256) void k_agg128(const unsigned short* __restrict__ h,
                                                const float* __restrict__ dinv,
                                                const int* __restrict__ rp,
                                                const int* __restrict__ col,
                                                const float* __restrict__ val,
                                                const float* __restrict__ bias,
                                                unsigned short* __restrict__ outb) {
    int node = blockIdx.x * 16 + (threadIdx.x >> 4);
    int sl = threadIdx.x & 15;
    if (node >= NN) return;
    float a[8];
    AGG_CORE(h, node, sl, a);
    float4 bz0 = ((const float4*)bias)[sl * 2];
    float4 bz1 = ((const float4*)bias)[sl * 2 + 1];
    float bb[8] = {bz0.x, bz0.y, bz0.z, bz0.w, bz1.x, bz1.y, bz1.z, bz1.w};
    us8 r;
    #pragma unroll
    for (int j = 0; j < 8; ++j) r[j] = f2b(fmaxf(a[j] + bb[j], 0.f));
    ((us8*)(outb + (size_t)node * DD))[sl] = r;
}

// agg + bias + relu + row-L2-normalize + residual avg: A=(norm+A)/2 fp32, Abf=bf16(A)
__global__ __launch_bounds__(256) void k_agg128_nr(const unsigned short* __restrict__ h,
                                                   const float* __restrict__ dinv,
                                                   const int* __restrict__ rp,
                                                   const int* __restrict__ col,
                                                   const float* __restrict__ val,
                                                   const float* __restrict__ bias,
                                                   float* __restrict__ A,
                                                   unsigned short* __restrict__ Abf) {
    int node = blockIdx.x * 16 + (threadIdx.x >> 4);
    int sl = threadIdx.x & 15;
    if (node >= NN) return;
    float a[8];
    AGG_CORE(h, node, sl, a);
    float4 bz0 = ((const float4*)bias)[sl * 2];
    float4 bz1 = ((const float4*)bias)[sl * 2 + 1];
    float bb[8] = {bz0.x, bz0.y, bz0.z, bz0.w, bz1.x, bz1.y, bz1.z, bz1.w};
    float ss = 0.f;
    #pragma unroll
    for (int j = 0; j < 8; ++j) {
        a[j] = fmaxf(a[j] + bb[j], 0.f);
        ss += a[j] * a[j];
    }
    ss += __shfl_xor(ss, 1);
    ss += __shfl_xor(ss, 2);
    ss += __shfl_xor(ss, 4);
    ss += __shfl_xor(ss, 8);
    float sc = 1.0f / fmaxf(sqrtf(ss), 1e-12f);
    float4 a0 = ((const float4*)(A + (size_t)node * DD))[sl * 2];
    float4 a1 = ((const float4*)(A + (size_t)node * DD))[sl * 2 + 1];
    float av[8] = {a0.x, a0.y, a0.z, a0.w, a1.x, a1.y, a1.z, a1.w};
    us8 rb;
    #pragma unroll
    for (int j = 0; j < 8; ++j) {
        av[j] = (a[j] * sc + av[j]) * 0.5f;
        rb[j] = f2b(av[j]);
    }
    float4 o0 = {av[0], av[1], av[2], av[3]};
    float4 o1 = {av[4], av[5], av[6], av[7]};
    ((float4*)(A + (size_t)node * DD))[sl * 2] = o0;
    ((float4*)(A + (size_t)node * DD))[sl * 2 + 1] = o1;
    ((us8*)(Abf + (size_t)node * DD))[sl] = rb;
}

// plain agg (no bias/relu) -> bf16, for the commuted final layer
__global__ __launch_bounds__(256) void k_agg_plain(const unsigned short* __restrict__ h,
                                                   const float* __restrict__ dinv,
                                                   const int* __restrict__ rp,
                                                   const int* __restrict__ col,
                                                   const float* __restrict__ val,
                                                   unsigned short* __restrict__ outb) {
    int node = blockIdx.x * 16 + (threadIdx.x >> 4);
    int sl = threadIdx.x & 15;
    if (node >= NN) return;
    float a[8];
    AGG_CORE(h, node, sl, a);
    us8 r;
    #pragma unroll
    for (int j = 0; j < 8; ++j) r[j] = f2b(a[j]);
    ((us8*)(outb + (size_t)node * DD))[sl] = r;
}

__global__ __launch_bounds__(256) void k_logsm(const float* __restrict__ Cb,
                                               float* __restrict__ out) {
    int node = blockIdx.x * 4 + (threadIdx.x >> 6);
    int lane = threadIdx.x & 63;
    if (node >= NN) return;
    float v = (lane < CC) ? Cb[(size_t)node * CC + lane] : -3.0e38f;
    float m = v;
    #pragma unroll
    for (int off = 32; off > 0; off >>= 1) m = fmaxf(m, __shfl_xor(m, off));
    float e = (lane < CC) ? expf(v - m) : 0.f;
    float s = e;
    #pragma unroll
    for (int off = 32; off > 0; off >>= 1) s += __shfl_xor(s, off);
    if (lane < CC) out[(size_t)node * CC + lane] = v - m - logf(s);
}

// ---------------- launch ----------------

extern "C" void kernel_launch(void* const* d_in, const int* in_sizes, int n_in,
                              void* d_out, int out_size, void* d_ws, size_t ws_size,
                              hipStream_t stream) {
    const float* x  = (const float*)d_in[0];
    const int*   ei = (const int*)d_in[1];
    const float* ew = (const float*)d_in[2];
    const float* Wb = (const float*)d_in[3];
    const float* bb = (const float*)d_in[4];
    const float* Wf = (const float*)d_in[5];
    const float* bf_ = (const float*)d_in[6];
    const int* src = ei;
    const int* dst = ei + EE;
    float* out = (float*)d_out;

    char* p = (char*)d_ws;
    float*          A    = (float*)p;          p += (size_t)NN * DD * 4;
    unsigned short* Abf  = (unsigned short*)p; p += (size_t)NN * DD * 2;
    unsigned short* Bbf  = (unsigned short*)p; p += (size_t)NN * DD * 2;
    unsigned short* Cbf  = (unsigned short*)p; p += (size_t)NN * DD * 2;
    unsigned short* Gbf  = (unsigned short*)p; p += (size_t)NN * DD * 2;
    float*          C40  = (float*)p;          p += (size_t)NN * CC * 4;
    unsigned short* WT   = (unsigned short*)p; p += (size_t)8 * DD * DD * 2;
    unsigned short* WfT  = (unsigned short*)p; p += (size_t)48 * DD * 2;
    float* dinv = (float*)p; p += (size_t)NN * 4;
    int*   cnt  = (int*)p;   p += (size_t)NN * 4;
    int*   rp   = (int*)p;   p += (size_t)(NN + 1) * 4;
    int*   fill = (int*)p;   p += (size_t)NN * 4;
    int*   col  = (int*)p;   p += (size_t)EE * 4;
    float* val  = (float*)p; p += (size_t)EE * 4;
    int*   partial = (int*)p; p += 128 * 4;

    hipMemsetAsync(dinv, 0, (size_t)NN * 4, stream);
    hipMemsetAsync(cnt,  0, (size_t)NN * 4, stream);
    hipMemsetAsync(fill, 0, (size_t)NN * 4, stream);

    k_deg_cnt<<<(EE + 255) / 256, 256, 0, stream>>>(dst, ew, dinv, cnt);
    k_dinv<<<(NN + 255) / 256, 256, 0, stream>>>(dinv);
    k_scan1<<<98, 256, 0, stream>>>(cnt, rp, partial);
    k_scan2<<<1, 128, 0, stream>>>(partial);
    k_scan3<<<(NN + 255) / 256, 256, 0, stream>>>(rp, partial);
    k_scatter<<<(EE + 255) / 256, 256, 0, stream>>>(src, dst, ew, dinv, rp, fill, col, val);

    k_prep_w<<<(8 * DD * DD + 255) / 256, 256, 0, stream>>>(Wb, WT);
    k_prep_wf<<<(48 * DD + 255) / 256, 256, 0, stream>>>(Wf, WfT);
    k_x2bf<<<(NN * DD / 4 + 255) / 256, 256, 0, stream>>>(x, A, Abf);

    for (int blk = 0; blk < 4; ++blk) {
        k_mm_mfma<<<(NN + 63) / 64, 256, 0, stream>>>(Abf, WT + (size_t)(2 * blk) * DD * DD, Bbf);
        k_agg128<<<(NN + 15) / 16, 256, 0, stream>>>(Bbf, dinv, rp, col, val, bb + (size_t)(2 * blk) * DD, Cbf);
        k_mm_mfma<<<(NN + 63) / 64, 256, 0, stream>>>(Cbf, WT + (size_t)(2 * blk + 1) * DD * DD, Bbf);
        k_agg128_nr<<<(NN + 15) / 16, 256, 0, stream>>>(Bbf, dinv, rp, col, val, bb + (size_t)(2 * blk + 1) * DD, A, Abf);
    }
    k_agg_plain<<<(NN + 15) / 16, 256, 0, stream>>>(Abf, dinv, rp, col, val, Gbf);
    k_mm_final<<<(NN + 63) / 64, 256, 0, stream>>>(Gbf, WfT, bf_, C40);
    k_logsm<<<(NN + 3) / 4, 256, 0, stream>>>(C40, out);
}

// Round 5
// 725.010 us; speedup vs baseline: 2.1366x; 1.0944x over previous
//
#include <hip/hip_runtime.h>
#include <math.h>

#define NN 100000
#define EE 640000
#define DD 128
#define CC 40
#define FIXS 4194304.0f  // 2^22 fixed-point scale for deg

typedef __bf16 bf16x8 __attribute__((ext_vector_type(8)));
typedef float f32x4 __attribute__((ext_vector_type(4)));
typedef unsigned short us8 __attribute__((ext_vector_type(8)));

__device__ inline unsigned short f2b(float f) {
    union { float f; unsigned u; } v; v.f = f;
    unsigned u = v.u;
    return (unsigned short)((u + 0x7FFFu + ((u >> 16) & 1u)) >> 16);
}
__device__ inline float b2f(unsigned short b) {
    union { unsigned u; float f; } v; v.u = ((unsigned)b) << 16;
    return v.f;
}

// ---------------- graph preprocessing ----------------

// one u64 atomic per edge: high32 += fixedpoint(w), low32 += 1.
// returned old low32 = this edge's slot within its dst bucket.
__global__ __launch_bounds__(256) void k_edge1(const int* __restrict__ dst,
                                               const float* __restrict__ w,
                                               unsigned long long* __restrict__ degcnt,
                                               int* __restrict__ pos) {
    int e = blockIdx.x * 256 + threadIdx.x;
    if (e < EE) {
        int d = dst[e];
        unsigned long long pk =
            ((unsigned long long)(unsigned)(w[e] * FIXS) << 32) | 1ull;
        unsigned long long old = atomicAdd(&degcnt[d], pk);
        pos[e] = (int)(old & 0xffffffffull);
    }
}

// scan over cnt (low32 of degcnt) + fold in dinv computation
__global__ __launch_bounds__(256) void k_scan1(const unsigned long long* __restrict__ degcnt,
                                               float* __restrict__ dinv,
                                               int* __restrict__ out,
                                               int* __restrict__ partial) {
    __shared__ int lds[256];
    int t = threadIdx.x;
    int base = blockIdx.x * 1024 + t * 4;
    int v[4]; int s = 0;
    #pragma unroll
    for (int j = 0; j < 4; ++j) {
        int idx = base + j;
        unsigned long long dc = (idx < NN) ? degcnt[idx] : 0ull;
        v[j] = (int)(dc & 0xffffffffull);
        s += v[j];
        if (idx < NN)
            dinv[idx] = rsqrtf((float)(unsigned)(dc >> 32) * (1.0f / FIXS) + 1.0f);
    }
    lds[t] = s;
    __syncthreads();
    for (int off = 1; off < 256; off <<= 1) {
        int x = lds[t];
        int y = (t >= off) ? lds[t - off] : 0;
        __syncthreads();
        lds[t] = x + y;
        __syncthreads();
    }
    int excl = lds[t] - s;
    if (t == 255) partial[blockIdx.x] = lds[255];
    int run = excl;
    #pragma unroll
    for (int j = 0; j < 4; ++j) {
        int idx = base + j;
        if (idx < NN) out[idx] = run;
        run += v[j];
    }
}

__global__ __launch_bounds__(128) void k_scan2(int* __restrict__ partial) {
    __shared__ int lds[128];
    int t = threadIdx.x;
    int v = (t < 98) ? partial[t] : 0;
    lds[t] = v;
    __syncthreads();
    for (int off = 1; off < 128; off <<= 1) {
        int x = lds[t];
        int y = (t >= off) ? lds[t - off] : 0;
        __syncthreads();
        lds[t] = x + y;
        __syncthreads();
    }
    if (t < 98) partial[t] = lds[t] - v;
}

__global__ __launch_bounds__(256) void k_scan3(int* __restrict__ rp,
                                               const int* __restrict__ partial) {
    int i = blockIdx.x * 256 + threadIdx.x;
    if (i < NN) rp[i] += partial[i >> 10];
    if (i == 0) rp[NN] = EE;
}

// atomic-free scatter using precomputed slots
__global__ __launch_bounds__(256) void k_scatter(const int* __restrict__ src,
                                                 const int* __restrict__ dst,
                                                 const float* __restrict__ w,
                                                 const float* __restrict__ dinv,
                                                 const int* __restrict__ rp,
                                                 const int* __restrict__ pos,
                                                 int* __restrict__ col,
                                                 float* __restrict__ val) {
    int e = blockIdx.x * 256 + threadIdx.x;
    if (e < EE) {
        int s = src[e], d = dst[e];
        int p = rp[d] + pos[e];
        col[p] = s;
        val[p] = dinv[s] * w[e] * dinv[d];
    }
}

// ---------------- weight / input prep ----------------

__global__ __launch_bounds__(256) void k_prep_w(const float* __restrict__ Wb,
                                                unsigned short* __restrict__ WT) {
    int idx = blockIdx.x * 256 + threadIdx.x;
    if (idx >= 8 * DD * DD) return;
    int m = idx >> 14;
    int n = (idx >> 7) & 127;
    int k = idx & 127;
    WT[idx] = f2b(Wb[(size_t)m * DD * DD + (size_t)k * DD + n]);
}

__global__ __launch_bounds__(256) void k_prep_wf(const float* __restrict__ Wf,
                                                 unsigned short* __restrict__ WfT) {
    int idx = blockIdx.x * 256 + threadIdx.x;
    if (idx >= 48 * DD) return;
    int n = idx >> 7;
    int k = idx & 127;
    WfT[idx] = (n < CC) ? f2b(Wf[(size_t)k * CC + n]) : 0;
}

__global__ __launch_bounds__(256) void k_x2bf(const float* __restrict__ x,
                                              float* __restrict__ A,
                                              unsigned short* __restrict__ Abf) {
    int idx = blockIdx.x * 256 + threadIdx.x;
    if (idx >= NN * DD / 4) return;
    float4 v = ((const float4*)x)[idx];
    ((float4*)A)[idx] = v;
    ushort4 r;
    r.x = f2b(v.x); r.y = f2b(v.y); r.z = f2b(v.z); r.w = f2b(v.w);
    ((ushort4*)Abf)[idx] = r;
}

// ---------------- bf16 MFMA matmul: H[N,128] = X[N,128] @ W ----------------
__global__ __launch_bounds__(256) void k_mm_mfma(const unsigned short* __restrict__ X,
                                                 const unsigned short* __restrict__ WT,
                                                 unsigned short* __restrict__ H) {
    int wid = threadIdx.x >> 6;
    int lane = threadIdx.x & 63;
    int r0 = blockIdx.x * 64 + wid * 16;
    int sl = lane & 15, g = lane >> 4;
    int arow = r0 + sl;
    if (arow >= NN) arow = NN - 1;

    f32x4 acc[8];
    #pragma unroll
    for (int n = 0; n < 8; ++n) acc[n] = (f32x4){0.f, 0.f, 0.f, 0.f};

    const bf16x8* xrow = (const bf16x8*)(X + (size_t)arow * DD);
    #pragma unroll
    for (int kc = 0; kc < 4; ++kc) {
        bf16x8 a = xrow[kc * 4 + g];
        #pragma unroll
        for (int n = 0; n < 8; ++n) {
            const bf16x8* wrow = (const bf16x8*)(WT + (size_t)(n * 16 + sl) * DD);
            bf16x8 b = wrow[kc * 4 + g];
            acc[n] = __builtin_amdgcn_mfma_f32_16x16x32_bf16(a, b, acc[n], 0, 0, 0);
        }
    }
    #pragma unroll
    for (int n = 0; n < 8; ++n) {
        #pragma unroll
        for (int v = 0; v < 4; ++v) {
            int row = r0 + g * 4 + v;
            if (row < NN) H[(size_t)row * DD + n * 16 + sl] = f2b(acc[n][v]);
        }
    }
}

// final projection + fused log_softmax:
// out[N,40] = log_softmax(G[N,128] @ WfT^T + bf)
__global__ __launch_bounds__(256) void k_mm_final(const unsigned short* __restrict__ X,
                                                  const unsigned short* __restrict__ WfT,
                                                  const float* __restrict__ bf_,
                                                  float* __restrict__ out) {
    int wid = threadIdx.x >> 6;
    int lane = threadIdx.x & 63;
    int r0 = blockIdx.x * 64 + wid * 16;
    int sl = lane & 15, g = lane >> 4;
    int arow = r0 + sl;
    if (arow >= NN) arow = NN - 1;

    f32x4 acc[3];
    #pragma unroll
    for (int n = 0; n < 3; ++n) acc[n] = (f32x4){0.f, 0.f, 0.f, 0.f};

    const bf16x8* xrow = (const bf16x8*)(X + (size_t)arow * DD);
    #pragma unroll
    for (int kc = 0; kc < 4; ++kc) {
        bf16x8 a = xrow[kc * 4 + g];
        #pragma unroll
        for (int n = 0; n < 3; ++n) {
            const bf16x8* wrow = (const bf16x8*)(WfT + (size_t)(n * 16 + sl) * DD);
            bf16x8 b = wrow[kc * 4 + g];
            acc[n] = __builtin_amdgcn_mfma_f32_16x16x32_bf16(a, b, acc[n], 0, 0, 0);
        }
    }
    // lane (g,sl) holds cols n*16+sl of rows r0+g*4+v. log_softmax across the
    // 40 cols = per-lane max/sum over n, then shfl_xor reduce over sl (bits 0-3).
    #pragma unroll
    for (int v = 0; v < 4; ++v) {
        int row = r0 + g * 4 + v;
        float vv[3];
        #pragma unroll
        for (int n = 0; n < 3; ++n) {
            int c = n * 16 + sl;
            vv[n] = (c < CC) ? acc[n][v] + bf_[c] : -3.0e38f;
        }
        float m = fmaxf(fmaxf(vv[0], vv[1]), vv[2]);
        m = fmaxf(m, __shfl_xor(m, 1));
        m = fmaxf(m, __shfl_xor(m, 2));
        m = fmaxf(m, __shfl_xor(m, 4));
        m = fmaxf(m, __shfl_xor(m, 8));
        float s = 0.f;
        #pragma unroll
        for (int n = 0; n < 3; ++n)
            s += (n * 16 + sl < CC) ? expf(vv[n] - m) : 0.f;
        s += __shfl_xor(s, 1);
        s += __shfl_xor(s, 2);
        s += __shfl_xor(s, 4);
        s += __shfl_xor(s, 8);
        float ls = logf(s);
        #pragma unroll
        for (int n = 0; n < 3; ++n) {
            int c = n * 16 + sl;
            if (row < NN && c < CC) out[(size_t)row * CC + c] = vv[n] - m - ls;
        }
    }
}

// ---------------- aggregation (16 lanes/node, bf16 rows, 4-way MLP) ----------------

#define AGG_CORE(h_, node_, sl_, a_)                                        \
    {                                                                       \
        float dv = dinv[node_];                                             \
        float dv2 = dv * dv;                                                \
        us8 m_ = ((const us8*)(h_ + (size_t)node_ * DD))[sl_];              \
        _Pragma("unroll")                                                   \
        for (int j = 0; j < 8; ++j) a_[j] = dv2 * b2f(m_[j]);               \
        int e = rp[node_], end = rp[node_ + 1];                             \
        for (; e + 4 <= end; e += 4) {                                      \
            int s0 = col[e], s1 = col[e + 1], s2 = col[e + 2], s3 = col[e + 3]; \
            float v0 = val[e], v1 = val[e + 1], v2 = val[e + 2], v3 = val[e + 3]; \
            us8 q0 = ((const us8*)(h_ + (size_t)s0 * DD))[sl_];             \
            us8 q1 = ((const us8*)(h_ + (size_t)s1 * DD))[sl_];             \
            us8 q2 = ((const us8*)(h_ + (size_t)s2 * DD))[sl_];             \
            us8 q3 = ((const us8*)(h_ + (size_t)s3 * DD))[sl_];             \
            _Pragma("unroll")                                               \
            for (int j = 0; j < 8; ++j)                                     \
                a_[j] += (v0 * b2f(q0[j]) + v1 * b2f(q1[j]))                \
                       + (v2 * b2f(q2[j]) + v3 * b2f(q3[j]));               \
        }                                                                   \
        for (; e < end; ++e) {                                              \
            int s0 = col[e];                                                \
            float v0 = val[e];                                              \
            us8 q0 = ((const us8*)(h_ + (size_t)s0 * DD))[sl_];             \
            _Pragma("unroll")                                               \
            for (int j = 0; j < 8; ++j) a_[j] += v0 * b2f(q0[j]);           \
        }                                                                   \
    }

__global__ __launch_bounds__(256) void k_agg128(const unsigned short* __restrict__ h,
                                                const float* __restrict__ dinv,
                                                const int* __restrict__ rp,
                                                const int* __restrict__ col,
                                                const float* __restrict__ val,
                                                const float* __restrict__ bias,
                                                unsigned short* __restrict__ outb) {
    int node = blockIdx.x * 16 + (threadIdx.x >> 4);
    int sl = threadIdx.x & 15;
    if (node >= NN) return;
    float a[8];
    AGG_CORE(h, node, sl, a);
    float4 bz0 = ((const float4*)bias)[sl * 2];
    float4 bz1 = ((const float4*)bias)[sl * 2 + 1];
    float bb[8] = {bz0.x, bz0.y, bz0.z, bz0.w, bz1.x, bz1.y, bz1.z, bz1.w};
    us8 r;
    #pragma unroll
    for (int j = 0; j < 8; ++j) r[j] = f2b(fmaxf(a[j] + bb[j], 0.f));
    ((us8*)(outb + (size_t)node * DD))[sl] = r;
}

__global__ __launch_bounds__(256) void k_agg128_nr(const unsigned short* __restrict__ h,
                                                   const float* __restrict__ dinv,
                                                   const int* __restrict__ rp,
                                                   const int* __restrict__ col,
                                                   const float* __restrict__ val,
                                                   const float* __restrict__ bias,
                                                   float* __restrict__ A,
                                                   unsigned short* __restrict__ Abf) {
    int node = blockIdx.x * 16 + (threadIdx.x >> 4);
    int sl = threadIdx.x & 15;
    if (node >= NN) return;
    float a[8];
    AGG_CORE(h, node, sl, a);
    float4 bz0 = ((const float4*)bias)[sl * 2];
    float4 bz1 = ((const float4*)bias)[sl * 2 + 1];
    float bb[8] = {bz0.x, bz0.y, bz0.z, bz0.w, bz1.x, bz1.y, bz1.z, bz1.w};
    float ss = 0.f;
    #pragma unroll
    for (int j = 0; j < 8; ++j) {
        a[j] = fmaxf(a[j] + bb[j], 0.f);
        ss += a[j] * a[j];
    }
    ss += __shfl_xor(ss, 1);
    ss += __shfl_xor(ss, 2);
    ss += __shfl_xor(ss, 4);
    ss += __shfl_xor(ss, 8);
    float sc = 1.0f / fmaxf(sqrtf(ss), 1e-12f);
    float4 a0 = ((const float4*)(A + (size_t)node * DD))[sl * 2];
    float4 a1 = ((const float4*)(A + (size_t)node * DD))[sl * 2 + 1];
    float av[8] = {a0.x, a0.y, a0.z, a0.w, a1.x, a1.y, a1.z, a1.w};
    us8 rb;
    #pragma unroll
    for (int j = 0; j < 8; ++j) {
        av[j] = (a[j] * sc + av[j]) * 0.5f;
        rb[j] = f2b(av[j]);
    }
    float4 o0 = {av[0], av[1], av[2], av[3]};
    float4 o1 = {av[4], av[5], av[6], av[7]};
    ((float4*)(A + (size_t)node * DD))[sl * 2] = o0;
    ((float4*)(A + (size_t)node * DD))[sl * 2 + 1] = o1;
    ((us8*)(Abf + (size_t)node * DD))[sl] = rb;
}

__global__ __launch_bounds__(256) void k_agg_plain(const unsigned short* __restrict__ h,
                                                   const float* __restrict__ dinv,
                                                   const int* __restrict__ rp,
                                                   const int* __restrict__ col,
                                                   const float* __restrict__ val,
                                                   unsigned short* __restrict__ outb) {
    int node = blockIdx.x * 16 + (threadIdx.x >> 4);
    int sl = threadIdx.x & 15;
    if (node >= NN) return;
    float a[8];
    AGG_CORE(h, node, sl, a);
    us8 r;
    #pragma unroll
    for (int j = 0; j < 8; ++j) r[j] = f2b(a[j]);
    ((us8*)(outb + (size_t)node * DD))[sl] = r;
}

// ---------------- launch ----------------

extern "C" void kernel_launch(void* const* d_in, const int* in_sizes, int n_in,
                              void* d_out, int out_size, void* d_ws, size_t ws_size,
                              hipStream_t stream) {
    const float* x  = (const float*)d_in[0];
    const int*   ei = (const int*)d_in[1];
    const float* ew = (const float*)d_in[2];
    const float* Wb = (const float*)d_in[3];
    const float* bb = (const float*)d_in[4];
    const float* Wf = (const float*)d_in[5];
    const float* bf_ = (const float*)d_in[6];
    const int* src = ei;
    const int* dst = ei + EE;
    float* out = (float*)d_out;

    char* p = (char*)d_ws;
    float*              A      = (float*)p;              p += (size_t)NN * DD * 4;
    unsigned short*     Abf    = (unsigned short*)p;     p += (size_t)NN * DD * 2;
    unsigned short*     Bbf    = (unsigned short*)p;     p += (size_t)NN * DD * 2;
    unsigned short*     Cbf    = (unsigned short*)p;     p += (size_t)NN * DD * 2;
    unsigned short*     Gbf    = (unsigned short*)p;     p += (size_t)NN * DD * 2;
    unsigned short*     WT     = (unsigned short*)p;     p += (size_t)8 * DD * DD * 2;
    unsigned short*     WfT    = (unsigned short*)p;     p += (size_t)48 * DD * 2;
    unsigned long long* degcnt = (unsigned long long*)p; p += (size_t)NN * 8;
    float* dinv = (float*)p; p += (size_t)NN * 4;
    int*   rp   = (int*)p;   p += (size_t)(NN + 1) * 4;
    int*   pos  = (int*)p;   p += (size_t)EE * 4;
    int*   col  = (int*)p;   p += (size_t)EE * 4;
    float* val  = (float*)p; p += (size_t)EE * 4;
    int*   partial = (int*)p; p += 128 * 4;

    hipMemsetAsync(degcnt, 0, (size_t)NN * 8, stream);

    k_edge1<<<(EE + 255) / 256, 256, 0, stream>>>(dst, ew, degcnt, pos);
    k_scan1<<<98, 256, 0, stream>>>(degcnt, dinv, rp, partial);
    k_scan2<<<1, 128, 0, stream>>>(partial);
    k_scan3<<<(NN + 255) / 256, 256, 0, stream>>>(rp, partial);
    k_scatter<<<(EE + 255) / 256, 256, 0, stream>>>(src, dst, ew, dinv, rp, pos, col, val);

    k_prep_w<<<(8 * DD * DD + 255) / 256, 256, 0, stream>>>(Wb, WT);
    k_prep_wf<<<(48 * DD + 255) / 256, 256, 0, stream>>>(Wf, WfT);
    k_x2bf<<<(NN * DD / 4 + 255) / 256, 256, 0, stream>>>(x, A, Abf);

    for (int blk = 0; blk < 4; ++blk) {
        k_mm_mfma<<<(NN + 63) / 64, 256, 0, stream>>>(Abf, WT + (size_t)(2 * blk) * DD * DD, Bbf);
        k_agg128<<<(NN + 15) / 16, 256, 0, stream>>>(Bbf, dinv, rp, col, val, bb + (size_t)(2 * blk) * DD, Cbf);
        k_mm_mfma<<<(NN + 63) / 64, 256, 0, stream>>>(Cbf, WT + (size_t)(2 * blk + 1) * DD * DD, Bbf);
        k_agg128_nr<<<(NN + 15) / 16, 256, 0, stream>>>(Bbf, dinv, rp, col, val, bb + (size_t)(2 * blk + 1) * DD, A, Abf);
    }
    k_agg_plain<<<(NN + 15) / 16, 256, 0, stream>>>(Abf, dinv, rp, col, val, Gbf);
    k_mm_final<<<(NN + 63) / 64, 256, 0, stream>>>(Gbf, WfT, bf_, out);
}

// Round 6
// 665.952 us; speedup vs baseline: 2.3261x; 1.0887x over previous
//
#include <hip/hip_runtime.h>
#include <math.h>

#define NN 100000
#define EE 640000
#define DD 128
#define CC 40
#define FIXS 4194304.0f  // 2^22 fixed-point scale for deg

typedef __bf16 bf16x8 __attribute__((ext_vector_type(8)));
typedef float f32x4 __attribute__((ext_vector_type(4)));
typedef unsigned short us8 __attribute__((ext_vector_type(8)));

__device__ inline unsigned short f2b(float f) {
    union { float f; unsigned u; } v; v.f = f;
    unsigned u = v.u;
    return (unsigned short)((u + 0x7FFFu + ((u >> 16) & 1u)) >> 16);
}
__device__ inline float b2f(unsigned short b) {
    union { unsigned u; float f; } v; v.u = ((unsigned)b) << 16;
    return v.f;
}

// ---------------- graph preprocessing ----------------

// one u64 atomic per edge: high32 += fixedpoint(w), low32 += 1.
// returned old low32 = this edge's slot within its dst bucket.
__global__ __launch_bounds__(256) void k_edge1(const int* __restrict__ dst,
                                               const float* __restrict__ w,
                                               unsigned long long* __restrict__ degcnt,
                                               int* __restrict__ pos) {
    int e = blockIdx.x * 256 + threadIdx.x;
    if (e < EE) {
        int d = dst[e];
        unsigned long long pk =
            ((unsigned long long)(unsigned)(w[e] * FIXS) << 32) | 1ull;
        unsigned long long old = atomicAdd(&degcnt[d], pk);
        pos[e] = (int)(old & 0xffffffffull);
    }
}

// scan over cnt (low32 of degcnt) + fold in dinv computation
__global__ __launch_bounds__(256) void k_scan1(const unsigned long long* __restrict__ degcnt,
                                               float* __restrict__ dinv,
                                               int* __restrict__ out,
                                               int* __restrict__ partial) {
    __shared__ int lds[256];
    int t = threadIdx.x;
    int base = blockIdx.x * 1024 + t * 4;
    int v[4]; int s = 0;
    #pragma unroll
    for (int j = 0; j < 4; ++j) {
        int idx = base + j;
        unsigned long long dc = (idx < NN) ? degcnt[idx] : 0ull;
        v[j] = (int)(dc & 0xffffffffull);
        s += v[j];
        if (idx < NN)
            dinv[idx] = rsqrtf((float)(unsigned)(dc >> 32) * (1.0f / FIXS) + 1.0f);
    }
    lds[t] = s;
    __syncthreads();
    for (int off = 1; off < 256; off <<= 1) {
        int x = lds[t];
        int y = (t >= off) ? lds[t - off] : 0;
        __syncthreads();
        lds[t] = x + y;
        __syncthreads();
    }
    int excl = lds[t] - s;
    if (t == 255) partial[blockIdx.x] = lds[255];
    int run = excl;
    #pragma unroll
    for (int j = 0; j < 4; ++j) {
        int idx = base + j;
        if (idx < NN) out[idx] = run;
        run += v[j];
    }
}

__global__ __launch_bounds__(128) void k_scan2(int* __restrict__ partial) {
    __shared__ int lds[128];
    int t = threadIdx.x;
    int v = (t < 98) ? partial[t] : 0;
    lds[t] = v;
    __syncthreads();
    for (int off = 1; off < 128; off <<= 1) {
        int x = lds[t];
        int y = (t >= off) ? lds[t - off] : 0;
        __syncthreads();
        lds[t] = x + y;
        __syncthreads();
    }
    if (t < 98) partial[t] = lds[t] - v;
}

__global__ __launch_bounds__(256) void k_scan3(int* __restrict__ rp,
                                               const int* __restrict__ partial) {
    int i = blockIdx.x * 256 + threadIdx.x;
    if (i < NN) rp[i] += partial[i >> 10];
    if (i == 0) rp[NN] = EE;
}

// atomic-free scatter using precomputed slots
__global__ __launch_bounds__(256) void k_scatter(const int* __restrict__ src,
                                                 const int* __restrict__ dst,
                                                 const float* __restrict__ w,
                                                 const float* __restrict__ dinv,
                                                 const int* __restrict__ rp,
                                                 const int* __restrict__ pos,
                                                 int* __restrict__ col,
                                                 float* __restrict__ val) {
    int e = blockIdx.x * 256 + threadIdx.x;
    if (e < EE) {
        int s = src[e], d = dst[e];
        int p = rp[d] + pos[e];
        col[p] = s;
        val[p] = dinv[s] * w[e] * dinv[d];
    }
}

// ---------------- weight / input prep ----------------

__global__ __launch_bounds__(256) void k_prep_w(const float* __restrict__ Wb,
                                                unsigned short* __restrict__ WT) {
    int idx = blockIdx.x * 256 + threadIdx.x;
    if (idx >= 8 * DD * DD) return;
    int m = idx >> 14;
    int n = (idx >> 7) & 127;
    int k = idx & 127;
    WT[idx] = f2b(Wb[(size_t)m * DD * DD + (size_t)k * DD + n]);
}

// WfT[n][k] = bf16(Wf[k][n]) for n<40, 0 for 40<=n<64
__global__ __launch_bounds__(256) void k_prep_wf(const float* __restrict__ Wf,
                                                 unsigned short* __restrict__ WfT) {
    int idx = blockIdx.x * 256 + threadIdx.x;
    if (idx >= 64 * DD) return;
    int n = idx >> 7;
    int k = idx & 127;
    WfT[idx] = (n < CC) ? f2b(Wf[(size_t)k * CC + n]) : 0;
}

__global__ __launch_bounds__(256) void k_x2bf(const float* __restrict__ x,
                                              unsigned short* __restrict__ Abf) {
    int idx = blockIdx.x * 256 + threadIdx.x;
    if (idx >= NN * DD / 4) return;
    float4 v = ((const float4*)x)[idx];
    ushort4 r;
    r.x = f2b(v.x); r.y = f2b(v.y); r.z = f2b(v.z); r.w = f2b(v.w);
    ((ushort4*)Abf)[idx] = r;
}

// ---------------- bf16 MFMA matmul: H[N,128] = X[N,128] @ W ----------------
__global__ __launch_bounds__(256) void k_mm_mfma(const unsigned short* __restrict__ X,
                                                 const unsigned short* __restrict__ WT,
                                                 unsigned short* __restrict__ H) {
    int wid = threadIdx.x >> 6;
    int lane = threadIdx.x & 63;
    int r0 = blockIdx.x * 64 + wid * 16;
    int sl = lane & 15, g = lane >> 4;
    int arow = r0 + sl;
    if (arow >= NN) arow = NN - 1;

    f32x4 acc[8];
    #pragma unroll
    for (int n = 0; n < 8; ++n) acc[n] = (f32x4){0.f, 0.f, 0.f, 0.f};

    const bf16x8* xrow = (const bf16x8*)(X + (size_t)arow * DD);
    #pragma unroll
    for (int kc = 0; kc < 4; ++kc) {
        bf16x8 a = xrow[kc * 4 + g];
        #pragma unroll
        for (int n = 0; n < 8; ++n) {
            const bf16x8* wrow = (const bf16x8*)(WT + (size_t)(n * 16 + sl) * DD);
            bf16x8 b = wrow[kc * 4 + g];
            acc[n] = __builtin_amdgcn_mfma_f32_16x16x32_bf16(a, b, acc[n], 0, 0, 0);
        }
    }
    #pragma unroll
    for (int n = 0; n < 8; ++n) {
        #pragma unroll
        for (int v = 0; v < 4; ++v) {
            int row = r0 + g * 4 + v;
            if (row < NN) H[(size_t)row * DD + n * 16 + sl] = f2b(acc[n][v]);
        }
    }
}

// projection into padded 64-col bf16: H48[N,64] = X[N,128] @ WfT^T (cols>=40 are 0)
__global__ __launch_bounds__(256) void k_mm40b(const unsigned short* __restrict__ X,
                                               const unsigned short* __restrict__ WfT,
                                               unsigned short* __restrict__ H) {
    int wid = threadIdx.x >> 6;
    int lane = threadIdx.x & 63;
    int r0 = blockIdx.x * 64 + wid * 16;
    int sl = lane & 15, g = lane >> 4;
    int arow = r0 + sl;
    if (arow >= NN) arow = NN - 1;

    f32x4 acc[4];
    #pragma unroll
    for (int n = 0; n < 4; ++n) acc[n] = (f32x4){0.f, 0.f, 0.f, 0.f};

    const bf16x8* xrow = (const bf16x8*)(X + (size_t)arow * DD);
    #pragma unroll
    for (int kc = 0; kc < 4; ++kc) {
        bf16x8 a = xrow[kc * 4 + g];
        #pragma unroll
        for (int n = 0; n < 4; ++n) {
            const bf16x8* wrow = (const bf16x8*)(WfT + (size_t)(n * 16 + sl) * DD);
            bf16x8 b = wrow[kc * 4 + g];
            acc[n] = __builtin_amdgcn_mfma_f32_16x16x32_bf16(a, b, acc[n], 0, 0, 0);
        }
    }
    #pragma unroll
    for (int n = 0; n < 4; ++n) {
        #pragma unroll
        for (int v = 0; v < 4; ++v) {
            int row = r0 + g * 4 + v;
            if (row < NN) H[(size_t)row * 64 + n * 16 + sl] = f2b(acc[n][v]);
        }
    }
}

// ---------------- aggregation cores ----------------

#define AGG_CORE(h_, node_, sl_, a_, STRIDE_)                               \
    {                                                                       \
        float dv = dinv[node_];                                             \
        float dv2 = dv * dv;                                                \
        us8 m_ = ((const us8*)(h_ + (size_t)node_ * STRIDE_))[sl_];         \
        _Pragma("unroll")                                                   \
        for (int j = 0; j < 8; ++j) a_[j] = dv2 * b2f(m_[j]);               \
        int e = rp[node_], end = rp[node_ + 1];                             \
        for (; e + 4 <= end; e += 4) {                                      \
            int s0 = col[e], s1 = col[e + 1], s2 = col[e + 2], s3 = col[e + 3]; \
            float v0 = val[e], v1 = val[e + 1], v2 = val[e + 2], v3 = val[e + 3]; \
            us8 q0 = ((const us8*)(h_ + (size_t)s0 * STRIDE_))[sl_];        \
            us8 q1 = ((const us8*)(h_ + (size_t)s1 * STRIDE_))[sl_];        \
            us8 q2 = ((const us8*)(h_ + (size_t)s2 * STRIDE_))[sl_];        \
            us8 q3 = ((const us8*)(h_ + (size_t)s3 * STRIDE_))[sl_];        \
            _Pragma("unroll")                                               \
            for (int j = 0; j < 8; ++j)                                     \
                a_[j] += (v0 * b2f(q0[j]) + v1 * b2f(q1[j]))                \
                       + (v2 * b2f(q2[j]) + v3 * b2f(q3[j]));               \
        }                                                                   \
        for (; e < end; ++e) {                                              \
            int s0 = col[e];                                                \
            float v0 = val[e];                                              \
            us8 q0 = ((const us8*)(h_ + (size_t)s0 * STRIDE_))[sl_];        \
            _Pragma("unroll")                                               \
            for (int j = 0; j < 8; ++j) a_[j] += v0 * b2f(q0[j]);           \
        }                                                                   \
    }

// agg + bias + relu -> bf16 (16 lanes/node)
__global__ __launch_bounds__(256) void k_agg128(const unsigned short* __restrict__ h,
                                                const float* __restrict__ dinv,
                                                const int* __restrict__ rp,
                                                const int* __restrict__ col,
                                                const float* __restrict__ val,
                                                const float* __restrict__ bias,
                                                unsigned short* __restrict__ outb) {
    int node = blockIdx.x * 16 + (threadIdx.x >> 4);
    int sl = threadIdx.x & 15;
    if (node >= NN) return;
    float a[8];
    AGG_CORE(h, node, sl, a, DD);
    float4 bz0 = ((const float4*)bias)[sl * 2];
    float4 bz1 = ((const float4*)bias)[sl * 2 + 1];
    float bb[8] = {bz0.x, bz0.y, bz0.z, bz0.w, bz1.x, bz1.y, bz1.z, bz1.w};
    us8 r;
    #pragma unroll
    for (int j = 0; j < 8; ++j) r[j] = f2b(fmaxf(a[j] + bb[j], 0.f));
    ((us8*)(outb + (size_t)node * DD))[sl] = r;
}

// agg + bias + relu + row-L2-normalize + residual avg, all-bf16 residual:
// Abf = bf16((normalize(relu(agg+b)) + Abf)/2)
__global__ __launch_bounds__(256) void k_agg128_nr(const unsigned short* __restrict__ h,
                                                   const float* __restrict__ dinv,
                                                   const int* __restrict__ rp,
                                                   const int* __restrict__ col,
                                                   const float* __restrict__ val,
                                                   const float* __restrict__ bias,
                                                   unsigned short* __restrict__ Abf) {
    int node = blockIdx.x * 16 + (threadIdx.x >> 4);
    int sl = threadIdx.x & 15;
    if (node >= NN) return;
    float a[8];
    AGG_CORE(h, node, sl, a, DD);
    float4 bz0 = ((const float4*)bias)[sl * 2];
    float4 bz1 = ((const float4*)bias)[sl * 2 + 1];
    float bb[8] = {bz0.x, bz0.y, bz0.z, bz0.w, bz1.x, bz1.y, bz1.z, bz1.w};
    float ss = 0.f;
    #pragma unroll
    for (int j = 0; j < 8; ++j) {
        a[j] = fmaxf(a[j] + bb[j], 0.f);
        ss += a[j] * a[j];
    }
    ss += __shfl_xor(ss, 1);
    ss += __shfl_xor(ss, 2);
    ss += __shfl_xor(ss, 4);
    ss += __shfl_xor(ss, 8);
    float sc = 1.0f / fmaxf(sqrtf(ss), 1e-12f);
    us8 oldb = ((const us8*)(Abf + (size_t)node * DD))[sl];
    us8 rb;
    #pragma unroll
    for (int j = 0; j < 8; ++j)
        rb[j] = f2b((a[j] * sc + b2f(oldb[j])) * 0.5f);
    ((us8*)(Abf + (size_t)node * DD))[sl] = rb;
}

// final: agg over 64-col padded H48 + bias + log_softmax -> out (8 lanes/node)
__global__ __launch_bounds__(256) void k_agg_final(const unsigned short* __restrict__ h,
                                                   const float* __restrict__ dinv,
                                                   const int* __restrict__ rp,
                                                   const int* __restrict__ col,
                                                   const float* __restrict__ val,
                                                   const float* __restrict__ bias,
                                                   float* __restrict__ out) {
    int node = blockIdx.x * 32 + (threadIdx.x >> 3);
    int sl = threadIdx.x & 7;
    if (node >= NN) return;
    float a[8];
    AGG_CORE(h, node, sl, a, 64);
    bool real = sl < 5;  // cols sl*8..sl*8+7 real iff sl<5 (40 cols)
    float vv[8];
    if (real) {
        float4 bz0 = ((const float4*)bias)[sl * 2];
        float4 bz1 = ((const float4*)bias)[sl * 2 + 1];
        float bb[8] = {bz0.x, bz0.y, bz0.z, bz0.w, bz1.x, bz1.y, bz1.z, bz1.w};
        #pragma unroll
        for (int j = 0; j < 8; ++j) vv[j] = a[j] + bb[j];
    } else {
        #pragma unroll
        for (int j = 0; j < 8; ++j) vv[j] = -3.0e38f;
    }
    float m = vv[0];
    #pragma unroll
    for (int j = 1; j < 8; ++j) m = fmaxf(m, vv[j]);
    m = fmaxf(m, __shfl_xor(m, 1));
    m = fmaxf(m, __shfl_xor(m, 2));
    m = fmaxf(m, __shfl_xor(m, 4));
    float s = 0.f;
    if (real) {
        #pragma unroll
        for (int j = 0; j < 8; ++j) s += expf(vv[j] - m);
    }
    s += __shfl_xor(s, 1);
    s += __shfl_xor(s, 2);
    s += __shfl_xor(s, 4);
    float ls = m + logf(s);
    if (real) {
        float4 o0 = {vv[0] - ls, vv[1] - ls, vv[2] - ls, vv[3] - ls};
        float4 o1 = {vv[4] - ls, vv[5] - ls, vv[6] - ls, vv[7] - ls};
        float* orow = out + (size_t)node * CC + sl * 8;
        *(float4*)(orow) = o0;
        *(float4*)(orow + 4) = o1;
    }
}

// ---------------- launch ----------------

extern "C" void kernel_launch(void* const* d_in, const int* in_sizes, int n_in,
                              void* d_out, int out_size, void* d_ws, size_t ws_size,
                              hipStream_t stream) {
    const float* x  = (const float*)d_in[0];
    const int*   ei = (const int*)d_in[1];
    const float* ew = (const float*)d_in[2];
    const float* Wb = (const float*)d_in[3];
    const float* bb = (const float*)d_in[4];
    const float* Wf = (const float*)d_in[5];
    const float* bf_ = (const float*)d_in[6];
    const int* src = ei;
    const int* dst = ei + EE;
    float* out = (float*)d_out;

    char* p = (char*)d_ws;
    unsigned short*     Abf    = (unsigned short*)p;     p += (size_t)NN * DD * 2;
    unsigned short*     Bbf    = (unsigned short*)p;     p += (size_t)NN * DD * 2;
    unsigned short*     Cbf    = (unsigned short*)p;     p += (size_t)NN * DD * 2;
    unsigned short*     H48    = (unsigned short*)p;     p += (size_t)NN * 64 * 2;
    unsigned short*     WT     = (unsigned short*)p;     p += (size_t)8 * DD * DD * 2;
    unsigned short*     WfT    = (unsigned short*)p;     p += (size_t)64 * DD * 2;
    unsigned long long* degcnt = (unsigned long long*)p; p += (size_t)NN * 8;
    float* dinv = (float*)p; p += (size_t)NN * 4;
    int*   rp   = (int*)p;   p += (size_t)(NN + 1) * 4;
    int*   pos  = (int*)p;   p += (size_t)EE * 4;
    int*   col  = (int*)p;   p += (size_t)EE * 4;
    float* val  = (float*)p; p += (size_t)EE * 4;
    int*   partial = (int*)p; p += 128 * 4;

    hipMemsetAsync(degcnt, 0, (size_t)NN * 8, stream);

    k_edge1<<<(EE + 255) / 256, 256, 0, stream>>>(dst, ew, degcnt, pos);
    k_scan1<<<98, 256, 0, stream>>>(degcnt, dinv, rp, partial);
    k_scan2<<<1, 128, 0, stream>>>(partial);
    k_scan3<<<(NN + 255) / 256, 256, 0, stream>>>(rp, partial);
    k_scatter<<<(EE + 255) / 256, 256, 0, stream>>>(src, dst, ew, dinv, rp, pos, col, val);

    k_prep_w<<<(8 * DD * DD + 255) / 256, 256, 0, stream>>>(Wb, WT);
    k_prep_wf<<<(64 * DD + 255) / 256, 256, 0, stream>>>(Wf, WfT);
    k_x2bf<<<(NN * DD / 4 + 255) / 256, 256, 0, stream>>>(x, Abf);

    for (int blk = 0; blk < 4; ++blk) {
        k_mm_mfma<<<(NN + 63) / 64, 256, 0, stream>>>(Abf, WT + (size_t)(2 * blk) * DD * DD, Bbf);
        k_agg128<<<(NN + 15) / 16, 256, 0, stream>>>(Bbf, dinv, rp, col, val, bb + (size_t)(2 * blk) * DD, Cbf);
        k_mm_mfma<<<(NN + 63) / 64, 256, 0, stream>>>(Cbf, WT + (size_t)(2 * blk + 1) * DD * DD, Bbf);
        k_agg128_nr<<<(NN + 15) / 16, 256, 0, stream>>>(Bbf, dinv, rp, col, val, bb + (size_t)(2 * blk + 1) * DD, Abf);
    }
    k_mm40b<<<(NN + 63) / 64, 256, 0, stream>>>(Abf, WfT, H48);
    k_agg_final<<<(NN + 31) / 32, 256, 0, stream>>>(H48, dinv, rp, col, val, bf_, out);
}